// Round 2
// baseline (741.714 us; speedup 1.0000x reference)
//
#include <hip/hip_runtime.h>
#include <hip/hip_bf16.h>

#define B_ 4096
#define T_ 2
#define S_ 4
#define E_ 128
#define NF_ 11
#define ID_ 55
#define MID_ 4
#define NG_ 6
#define SI_ 4
#define EPSf 1e-5f

// triu_indices(11, k=1) pairs
__device__ const int PR[55]={0,0,0,0,0,0,0,0,0,0,1,1,1,1,1,1,1,1,1,2,2,2,2,2,2,2,2,3,3,3,3,3,3,3,4,4,4,4,4,4,5,5,5,5,5,6,6,6,6,7,7,7,8,8,9};
__device__ const int PC[55]={1,2,3,4,5,6,7,8,9,10,2,3,4,5,6,7,8,9,10,3,4,5,6,7,8,9,10,4,5,6,7,8,9,10,5,6,7,8,9,10,6,7,8,9,10,7,8,9,10,8,9,10,9,10,10};

// -------- prep: repack gate_W E-part to [st][e][g] --------------------------
__global__ void k_prep(const float* __restrict__ gW, const float* __restrict__ lgW,
                       float* __restrict__ gw6f, float* __restrict__ lgw6f){
  int k = blockIdx.x*256 + threadIdx.x;
  if (k < 6144){
    int st = k/768, r = k%768, g = r/128, e = r%128;
    gw6f [(st*128+e)*6+g] = gW [(st*6+g)*132 + 4 + e];
    lgw6f[(st*128+e)*6+g] = lgW[(st*6+g)*132 + 4 + e];
  }
}

// -------- fields: gathers + user/item projections ---------------------------
__global__ __launch_bounds__(128) void k_fields(
    const int* __restrict__ cat, const float* __restrict__ num,
    const float* __restrict__ embT, const float* __restrict__ linT,
    const float* __restrict__ uW, const float* __restrict__ ub,
    const float* __restrict__ iW, const float* __restrict__ ib,
    const float* __restrict__ ulW, const float* __restrict__ ulb,
    const float* __restrict__ ilW, const float* __restrict__ ilb,
    float* __restrict__ fields, float* __restrict__ lfields)
{
  const int b = blockIdx.x, e = threadIdx.x;
  __shared__ float s_num[63];
  if (e < 63) s_num[e] = num[(size_t)b*63 + e];
  __syncthreads();
  const int* cb = cat + (size_t)b*10;
  float* fo = fields  + (size_t)b*NF_*E_;
  float* lo = lfields + (size_t)b*NF_*E_;
  for (int j = 0; j < 9; ++j){
    int id = cb[1+j] + j*1000;
    fo[j*E_+e] = embT[(size_t)id*E_+e];
    lo[j*E_+e] = linT[(size_t)id*E_+e];
  }
  float a0 = ub[e], a1 = ulb[e];
  for (int k = 0; k < 23; ++k){ float x = s_num[k]; a0 += x*uW[e*23+k]; a1 += x*ulW[e*23+k]; }
  fo[9*E_+e] = a0; lo[9*E_+e] = a1;
  float a2 = ib[e], a3 = ilb[e];
  for (int k = 0; k < 40; ++k){ float x = s_num[23+k]; a2 += x*iW[e*40+k]; a3 += x*ilW[e*40+k]; }
  fo[10*E_+e] = a2; lo[10*E_+e] = a3;
}

// -------- moe1: pe -> ein -> gates -> experts -> mix -> mask ----------------
__global__ __launch_bounds__(512) void k_moe1(
    const int* __restrict__ cat,
    const float* __restrict__ scen_emb, const float* __restrict__ task_emb,
    const float* __restrict__ st_w, const float* __restrict__ interact_w,
    const float* __restrict__ sb_W, const float* __restrict__ sb_b,
    const float* __restrict__ shexp_W, const float* __restrict__ shexp_b,
    const float* __restrict__ spexp_W, const float* __restrict__ spexp_b,
    const float* __restrict__ gate_W, const float* __restrict__ gate_b,
    const float* __restrict__ mask_W, const float* __restrict__ mask_b,
    const float* __restrict__ fields, const float* __restrict__ gw6f,
    float* __restrict__ m1)
{
  __shared__ float sm[14985];
  const int tid = threadIdx.x, b = blockIdx.x;
  const int scen = cat[(size_t)b*10];
  float* s_pe   = sm;          // 55*129
  float* s_fld  = sm + 7095;   // 11*128 (dead after pe build)
  float* s_glog = sm + 7095;   // 440*6 (overlaps s_fld)
  float* s_ein  = sm + 9735;   // 55*14
  float* s_sh   = sm + 10505;  // 55*16
  float* s_w    = sm + 11385;  // 8*220
  float* s_stig = sm + 13145;  // 48
  float* s_sbw  = sm + 13193;  // 14*128

  for (int k = tid; k < NF_*E_; k += 512) s_fld[k] = fields[(size_t)b*NF_*E_ + k];
  for (int k = tid; k < 14*E_;  k += 512) s_sbw[k] = sb_W[k];
  if (tid < 48){
    int st = tid/6, g = tid%6, t = st%T_;
    float stw = st_w[t*S_ + scen];
    float acc = gate_b[st*6+g];
    for (int i = 0; i < 4; ++i){
      float sti = scen_emb[scen*4+i] * task_emb[t*4+i] * stw;
      acc += sti * gate_W[(st*6+g)*132 + i];
    }
    s_stig[tid] = acc;
  }
  __syncthreads();
  for (int k = tid; k < ID_*E_; k += 512){
    int f = k >> 7, e = k & 127;
    s_pe[f*129+e] = s_fld[PR[f]*E_+e] * s_fld[PC[f]*E_+e] * interact_w[f];
  }
  __syncthreads();
  // gate logits: thread=(st,f) -> 6 accumulators
  if (tid < 440){
    int f = tid % 55, st = tid / 55;
    float acc[6];
    for (int g = 0; g < 6; ++g) acc[g] = s_stig[st*6+g];
    const float* gp = gw6f + st*E_*6;
    for (int e = 0; e < E_; ++e){
      float pv = s_pe[f*129+e];
      const float* g6 = gp + e*6;
      acc[0]+=pv*g6[0]; acc[1]+=pv*g6[1]; acc[2]+=pv*g6[2];
      acc[3]+=pv*g6[3]; acc[4]+=pv*g6[4]; acc[5]+=pv*g6[5];
    }
    for (int g = 0; g < 6; ++g) s_glog[(st*55+f)*6+g] = acc[g];
  }
  // ein: thread=(f,half) -> 7 accumulators
  if (tid < 110){
    int f = tid % 55, h = tid / 55;
    float acc[7];
    for (int ii = 0; ii < 7; ++ii) acc[ii] = sb_b[h*7+ii];
    for (int e = 0; e < E_; ++e){
      float pv = s_pe[f*129+e];
      for (int ii = 0; ii < 7; ++ii) acc[ii] += pv * s_sbw[(h*7+ii)*E_+e];
    }
    for (int ii = 0; ii < 7; ++ii) s_ein[f*14 + h*7 + ii] = acc[ii];
  }
  __syncthreads();
  // shared experts
  for (int o = tid; o < 880; o += 512){
    int f = o >> 4, j = o & 15;
    float acc = shexp_b[j];
    for (int i = 0; i < 14; ++i) acc += s_ein[f*14+i] * shexp_W[j*14+i];
    s_sh[o] = acc;
  }
  __syncthreads();
  // softmax + specific experts + mixture
  if (tid < 440){
    int st = tid / 55, f = tid % 55;
    float lg[6], mx = -1e30f;
    for (int g = 0; g < 6; ++g){ lg[g] = s_glog[(st*55+f)*6+g]; mx = fmaxf(mx, lg[g]); }
    float sum = 0.f;
    for (int g = 0; g < 6; ++g){ lg[g] = __expf(lg[g]-mx); sum += lg[g]; }
    float inv = 1.f/sum;
    float wv[4] = {0,0,0,0};
    for (int g = 0; g < 4; ++g){
      float gg = lg[g]*inv;
      for (int m = 0; m < 4; ++m) wv[m] += gg * s_sh[f*16 + g*4 + m];
    }
    for (int ee = 0; ee < 2; ++ee){
      float gg = lg[4+ee]*inv;
      for (int m = 0; m < 4; ++m){
        float acc = spexp_b[(st*2+ee)*4+m];
        const float* wp = spexp_W + ((st*2+ee)*4+m)*14;
        for (int i = 0; i < 14; ++i) acc += s_ein[f*14+i] * wp[i];
        wv[m] += gg*acc;
      }
    }
    for (int m = 0; m < 4; ++m) s_w[st*220 + f*4 + m] = wv[m];
  }
  __syncthreads();
  // mask matmul -> m_raw rows [st*55+o][b]
  if (tid < 440){
    int st = tid / 55, oo = tid % 55;
    float acc = mask_b[st*55+oo];
    const float* mw = mask_W + (size_t)(st*55+oo)*220;
    const float* wp = s_w + st*220;
    for (int i = 0; i < 220; ++i) acc += wp[i] * mw[i];
    m1[(size_t)(st*55+oo)*B_ + b] = acc;
  }
}

// -------- per-row batch stats (mean, rsqrt(var+eps)) ------------------------
__global__ __launch_bounds__(256) void k_stats(const float* __restrict__ x, float* __restrict__ stats){
  const int row = blockIdx.x, tid = threadIdx.x;
  const float* xr = x + (size_t)row*B_;
  float s = 0.f, s2 = 0.f;
  for (int i = tid; i < B_; i += 256){ float v = xr[i]; s += v; s2 += v*v; }
  for (int off = 32; off > 0; off >>= 1){ s += __shfl_down(s, off); s2 += __shfl_down(s2, off); }
  __shared__ float red[8];
  if ((tid & 63) == 0){ red[(tid>>6)*2] = s; red[(tid>>6)*2+1] = s2; }
  __syncthreads();
  if (tid == 0){
    float Ssum = red[0]+red[2]+red[4]+red[6], S2 = red[1]+red[3]+red[5]+red[7];
    float mean = Ssum*(1.f/B_), var = S2*(1.f/B_) - mean*mean;
    stats[row*2] = mean; stats[row*2+1] = rsqrtf(fmaxf(var, 0.f) + EPSf);
  }
}

// -------- inter: bn(m)->tanh->relu, weighted pe contraction -> h[:, :128] ---
__global__ __launch_bounds__(128) void k_inter(
    const int* __restrict__ cat, const float* __restrict__ fields,
    const float* __restrict__ m1, const float* __restrict__ stm,
    const float* __restrict__ att_W, const float* __restrict__ interact_w,
    float* __restrict__ hbuf)
{
  __shared__ float s_fld[NF_*E_];
  __shared__ float s_co[110];
  const int b = blockIdx.x, e = threadIdx.x;
  const int scen = cat[(size_t)b*10];
  for (int k = e; k < NF_*E_; k += 128) s_fld[k] = fields[(size_t)b*NF_*E_ + k];
  if (e < 110){
    int t = e/55, f = e%55, row = (scen*T_+t)*55 + f;
    float v = (m1[(size_t)row*B_+b] - stm[row*2]) * stm[row*2+1];
    v = fmaxf(tanhf(v), 0.f);
    s_co[e] = v * att_W[(scen*T_+t)*55 + f];
  }
  __syncthreads();
  float a0 = 0.f, a1 = 0.f;
  for (int f = 0; f < 55; ++f){
    float pe = s_fld[PR[f]*E_+e] * s_fld[PC[f]*E_+e] * interact_w[f];
    a0 += s_co[f]*pe; a1 += s_co[55+f]*pe;
  }
  hbuf[(size_t)(0*256+e)*B_ + b] = a0;
  hbuf[(size_t)(1*256+e)*B_ + b] = a1;
}

// -------- moe2 (linear path, F=11) + ltower ---------------------------------
__global__ __launch_bounds__(256) void k_moe2(
    const int* __restrict__ cat,
    const float* __restrict__ scen_emb, const float* __restrict__ task_emb, const float* __restrict__ st_w,
    const float* __restrict__ lsb_W, const float* __restrict__ lsb_b,
    const float* __restrict__ lshexp_W, const float* __restrict__ lshexp_b,
    const float* __restrict__ lspexp_W, const float* __restrict__ lspexp_b,
    const float* __restrict__ lgate_W, const float* __restrict__ lgate_b,
    const float* __restrict__ ltower_W, const float* __restrict__ ltower_b,
    const float* __restrict__ lfields, const float* __restrict__ lgw6f,
    float* __restrict__ lt1)
{
  __shared__ float sm[4469];
  const int tid = threadIdx.x, b = blockIdx.x;
  const int scen = cat[(size_t)b*10];
  float* s_lf = sm; float* s_glog = sm+1419; float* s_ein = sm+1947; float* s_sh = sm+2101;
  float* s_w = sm+2277; float* s_stig = sm+2629; float* s_sbw = sm+2677;

  for (int k = tid; k < NF_*E_; k += 256){ int f = k>>7, e = k&127; s_lf[f*129+e] = lfields[(size_t)b*NF_*E_+k]; }
  for (int k = tid; k < 14*E_;  k += 256) s_sbw[k] = lsb_W[k];
  if (tid < 48){
    int st = tid/6, g = tid%6, t = st%T_;
    float stw = st_w[t*S_ + scen];
    float acc = lgate_b[st*6+g];
    for (int i = 0; i < 4; ++i){
      float sti = scen_emb[scen*4+i] * task_emb[t*4+i] * stw;
      acc += sti * lgate_W[(st*6+g)*132 + i];
    }
    s_stig[tid] = acc;
  }
  __syncthreads();
  if (tid < 88){
    int f = tid % 11, st = tid / 11;
    float acc[6]; for (int g = 0; g < 6; ++g) acc[g] = s_stig[st*6+g];
    const float* gp = lgw6f + st*E_*6;
    for (int e = 0; e < E_; ++e){
      float xv = s_lf[f*129+e];
      const float* g6 = gp + e*6;
      acc[0]+=xv*g6[0]; acc[1]+=xv*g6[1]; acc[2]+=xv*g6[2];
      acc[3]+=xv*g6[3]; acc[4]+=xv*g6[4]; acc[5]+=xv*g6[5];
    }
    for (int g = 0; g < 6; ++g) s_glog[(st*11+f)*6+g] = acc[g];
  }
  if (tid < 22){
    int f = tid % 11, h = tid / 11;
    float acc[7];
    for (int ii = 0; ii < 7; ++ii) acc[ii] = lsb_b[h*7+ii];
    for (int e = 0; e < E_; ++e){
      float xv = s_lf[f*129+e];
      for (int ii = 0; ii < 7; ++ii) acc[ii] += xv * s_sbw[(h*7+ii)*E_+e];
    }
    for (int ii = 0; ii < 7; ++ii) s_ein[f*14 + h*7 + ii] = acc[ii];
  }
  __syncthreads();
  if (tid < 176){
    int f = tid >> 4, j = tid & 15;
    float acc = lshexp_b[j];
    for (int i = 0; i < 14; ++i) acc += s_ein[f*14+i] * lshexp_W[j*14+i];
    s_sh[tid] = acc;
  }
  __syncthreads();
  if (tid < 88){
    int st = tid / 11, f = tid % 11;
    float lg[6], mx = -1e30f;
    for (int g = 0; g < 6; ++g){ lg[g] = s_glog[(st*11+f)*6+g]; mx = fmaxf(mx, lg[g]); }
    float sum = 0.f;
    for (int g = 0; g < 6; ++g){ lg[g] = __expf(lg[g]-mx); sum += lg[g]; }
    float inv = 1.f/sum;
    float wv[4] = {0,0,0,0};
    for (int g = 0; g < 4; ++g){
      float gg = lg[g]*inv;
      for (int m = 0; m < 4; ++m) wv[m] += gg * s_sh[f*16 + g*4 + m];
    }
    for (int ee = 0; ee < 2; ++ee){
      float gg = lg[4+ee]*inv;
      for (int m = 0; m < 4; ++m){
        float acc = lspexp_b[(st*2+ee)*4+m];
        const float* wp = lspexp_W + ((st*2+ee)*4+m)*14;
        for (int i = 0; i < 14; ++i) acc += s_ein[f*14+i] * wp[i];
        wv[m] += gg*acc;
      }
    }
    for (int m = 0; m < 4; ++m) s_w[st*44 + f*4 + m] = wv[m];
  }
  __syncthreads();
  if (tid < 88){
    int st = tid / 11, oo = tid % 11;
    float acc = ltower_b[st*11+oo];
    const float* tw = ltower_W + (st*11+oo)*44;
    const float* wp = s_w + st*44;
    for (int i = 0; i < 44; ++i) acc += wp[i] * tw[i];
    lt1[(size_t)(st*11+oo)*B_ + b] = acc;
  }
}

// -------- linf: bn(lt)->softmax over fields, weighted lfields -> h[:,128:] --
__global__ __launch_bounds__(128) void k_linf(
    const int* __restrict__ cat, const float* __restrict__ lfields,
    const float* __restrict__ lt1, const float* __restrict__ stl,
    const float* __restrict__ bias_p, float* __restrict__ hbuf)
{
  __shared__ float s_lf[NF_*E_];
  __shared__ float s_lw[22];
  const int b = blockIdx.x, e = threadIdx.x;
  const int scen = cat[(size_t)b*10];
  for (int k = e; k < NF_*E_; k += 128) s_lf[k] = lfields[(size_t)b*NF_*E_ + k];
  if (e < 22){
    int t = e/11, f = e%11, row = (scen*T_+t)*11 + f;
    s_lw[e] = (lt1[(size_t)row*B_+b] - stl[row*2]) * stl[row*2+1];
  }
  __syncthreads();
  if (e < 2){
    int t = e; float mx = -1e30f;
    for (int f = 0; f < 11; ++f) mx = fmaxf(mx, s_lw[t*11+f]);
    float sum = 0.f;
    for (int f = 0; f < 11; ++f){ float x = __expf(s_lw[t*11+f]-mx); s_lw[t*11+f] = x; sum += x; }
    float inv = 1.f/sum;
    for (int f = 0; f < 11; ++f) s_lw[t*11+f] *= inv;
  }
  __syncthreads();
  for (int t = 0; t < 2; ++t){
    float acc = bias_p[(size_t)(t*S_+scen)*E_ + e];
    for (int f = 0; f < 11; ++f) acc += s_lw[t*11+f] * s_lf[f*E_+e];
    hbuf[(size_t)(t*256+128+e)*B_ + b] = acc;
  }
}

// -------- final MLP ---------------------------------------------------------
__global__ __launch_bounds__(256) void k_last1(const float* __restrict__ hbuf,
    const float* __restrict__ W1, const float* __restrict__ b1, float* __restrict__ h1){
  int bz = blockIdx.x, t = bz/80, r = bz%80, og = r/16, bc = r%16;
  __shared__ float s_w1[8*256];
  int tid = threadIdx.x;
  for (int k = tid; k < 2048; k += 256){
    int oo = k>>8, i = k&255;
    s_w1[k] = W1[(size_t)(t*40 + og*8 + oo)*256 + i];
  }
  __syncthreads();
  int b = bc*256 + tid;
  float acc[8];
  for (int oo = 0; oo < 8; ++oo) acc[oo] = b1[t*40 + og*8 + oo];
  for (int i = 0; i < 256; ++i){
    float hv = hbuf[(size_t)(t*256+i)*B_ + b];
    for (int oo = 0; oo < 8; ++oo) acc[oo] += hv * s_w1[oo*256+i];
  }
  for (int oo = 0; oo < 8; ++oo) h1[(size_t)(t*40 + og*8 + oo)*B_ + b] = acc[oo];
}

__global__ __launch_bounds__(256) void k_last2(const float* __restrict__ h1, const float* __restrict__ st1,
    const float* __restrict__ W2, const float* __restrict__ b2v, float* __restrict__ h2){
  int bz = blockIdx.x, t = bz/16, bc = bz%16, tid = threadIdx.x, b = bc*256 + tid;
  __shared__ float s_w2[1280];
  for (int k = tid; k < 1280; k += 256) s_w2[k] = W2[t*1280 + k];
  __syncthreads();
  float hv[40];
  for (int i = 0; i < 40; ++i){
    int row = t*40 + i;
    hv[i] = fmaxf((h1[(size_t)row*B_+b] - st1[row*2]) * st1[row*2+1], 0.f);
  }
  for (int o = 0; o < 32; ++o){
    float acc = b2v[t*32+o];
    for (int i = 0; i < 40; ++i) acc += hv[i] * s_w2[o*40+i];
    h2[(size_t)(t*32+o)*B_ + b] = acc;
  }
}

__global__ __launch_bounds__(256) void k_last3(const float* __restrict__ h2, const float* __restrict__ st2,
    const float* __restrict__ W3, const float* __restrict__ b3v, float* __restrict__ h3){
  int bz = blockIdx.x, t = bz/16, bc = bz%16, tid = threadIdx.x, b = bc*256 + tid;
  __shared__ float s_w3[256];
  if (tid < 256) s_w3[tid] = W3[t*256 + tid];
  __syncthreads();
  float hv[32];
  for (int i = 0; i < 32; ++i){
    int row = t*32 + i;
    hv[i] = fmaxf((h2[(size_t)row*B_+b] - st2[row*2]) * st2[row*2+1], 0.f);
  }
  for (int o = 0; o < 8; ++o){
    float acc = b3v[t*8+o];
    for (int i = 0; i < 32; ++i) acc += hv[i] * s_w3[o*32+i];
    h3[(size_t)(t*8+o)*B_ + b] = acc;
  }
}

__global__ __launch_bounds__(256) void k_out(const float* __restrict__ h3, const float* __restrict__ st3,
    const float* __restrict__ W4, const float* __restrict__ b4v, float* __restrict__ out){
  int idx = blockIdx.x*256 + threadIdx.x;
  int t = idx / B_, b = idx % B_;
  float acc = b4v[t];
  for (int i = 0; i < 8; ++i){
    int row = t*8 + i;
    float v = fmaxf((h3[(size_t)row*B_+b] - st3[row*2]) * st3[row*2+1], 0.f);
    acc += v * W4[t*8+i];
  }
  out[idx] = 1.f/(1.f + __expf(-acc));
}

extern "C" void kernel_launch(void* const* d_in, const int* in_sizes, int n_in,
                              void* d_out, int out_size, void* d_ws, size_t ws_size,
                              hipStream_t stream)
{
  const int*   cat      = (const int*)  d_in[0];
  const float* num      = (const float*)d_in[1];
  const float* embT     = (const float*)d_in[2];
  const float* linT     = (const float*)d_in[3];
  const float* uW = (const float*)d_in[4];  const float* ub = (const float*)d_in[5];
  const float* iW = (const float*)d_in[6];  const float* ib = (const float*)d_in[7];
  const float* ulW = (const float*)d_in[8]; const float* ulb = (const float*)d_in[9];
  const float* ilW = (const float*)d_in[10];const float* ilb = (const float*)d_in[11];
  const float* scen_emb = (const float*)d_in[12];
  const float* task_emb = (const float*)d_in[13];
  const float* st_w     = (const float*)d_in[14];
  const float* interact_w=(const float*)d_in[15];
  const float* sbW = (const float*)d_in[16]; const float* sbb = (const float*)d_in[17];
  const float* lsbW = (const float*)d_in[18];const float* lsbb = (const float*)d_in[19];
  const float* shW = (const float*)d_in[20]; const float* shb = (const float*)d_in[21];
  const float* spW = (const float*)d_in[22]; const float* spb = (const float*)d_in[23];
  const float* lshW = (const float*)d_in[24];const float* lshb = (const float*)d_in[25];
  const float* lspW = (const float*)d_in[26];const float* lspb = (const float*)d_in[27];
  const float* gW = (const float*)d_in[28];  const float* gb = (const float*)d_in[29];
  const float* lgW = (const float*)d_in[30]; const float* lgb = (const float*)d_in[31];
  const float* mW = (const float*)d_in[32];  const float* mb = (const float*)d_in[33];
  const float* attW = (const float*)d_in[34];
  const float* ltW = (const float*)d_in[35]; const float* ltb = (const float*)d_in[36];
  const float* biasP = (const float*)d_in[37];
  const float* W1 = (const float*)d_in[38];  const float* b1 = (const float*)d_in[39];
  const float* W2 = (const float*)d_in[40];  const float* b2v = (const float*)d_in[41];
  const float* W3 = (const float*)d_in[42];  const float* b3v = (const float*)d_in[43];
  const float* W4 = (const float*)d_in[44];  const float* b4v = (const float*)d_in[45];
  float* out = (float*)d_out;

  float* ws = (float*)d_ws;
  size_t o = 0;
  float* fieldsB  = ws + o; o += (size_t)B_*NF_*E_;
  float* lfieldsB = ws + o; o += (size_t)B_*NF_*E_;
  float* gw6f  = ws + o; o += 6144;
  float* lgw6f = ws + o; o += 6144;
  float* m1  = ws + o; o += (size_t)440*B_;
  float* stm = ws + o; o += 880;
  float* lt1 = ws + o; o += (size_t)88*B_;
  float* stl = ws + o; o += 176;
  float* hbuf = ws + o; o += (size_t)T_*256*B_;
  float* h1  = ws + o; o += (size_t)80*B_;
  float* st1 = ws + o; o += 160;
  float* h2  = ws + o; o += (size_t)64*B_;
  float* st2 = ws + o; o += 128;
  float* h3  = ws + o; o += (size_t)16*B_;
  float* st3 = ws + o; o += 32;

  k_prep<<<24, 256, 0, stream>>>(gW, lgW, gw6f, lgw6f);
  k_fields<<<B_, 128, 0, stream>>>(cat, num, embT, linT, uW, ub, iW, ib, ulW, ulb, ilW, ilb, fieldsB, lfieldsB);
  k_moe1<<<B_, 512, 0, stream>>>(cat, scen_emb, task_emb, st_w, interact_w, sbW, sbb, shW, shb,
                                 spW, spb, gW, gb, mW, mb, fieldsB, gw6f, m1);
  k_stats<<<440, 256, 0, stream>>>(m1, stm);
  k_inter<<<B_, 128, 0, stream>>>(cat, fieldsB, m1, stm, attW, interact_w, hbuf);
  k_moe2<<<B_, 256, 0, stream>>>(cat, scen_emb, task_emb, st_w, lsbW, lsbb, lshW, lshb,
                                 lspW, lspb, lgW, lgb, ltW, ltb, lfieldsB, lgw6f, lt1);
  k_stats<<<88, 256, 0, stream>>>(lt1, stl);
  k_linf<<<B_, 128, 0, stream>>>(cat, lfieldsB, lt1, stl, biasP, hbuf);
  k_last1<<<160, 256, 0, stream>>>(hbuf, W1, b1, h1);
  k_stats<<<80, 256, 0, stream>>>(h1, st1);
  k_last2<<<32, 256, 0, stream>>>(h1, st1, W2, b2v, h2);
  k_stats<<<64, 256, 0, stream>>>(h2, st2);
  k_last3<<<32, 256, 0, stream>>>(h2, st2, W3, b3v, h3);
  k_stats<<<16, 256, 0, stream>>>(h3, st3);
  k_out<<<32, 256, 0, stream>>>(h3, st3, W4, b4v, out);
}

// Round 3
// 585.160 us; speedup vs baseline: 1.2675x; 1.2675x over previous
//
#include <hip/hip_runtime.h>
#include <hip/hip_bf16.h>

#define B_ 4096
#define T_ 2
#define S_ 4
#define E_ 128
#define NF_ 11
#define ID_ 55
#define MID_ 4
#define NG_ 6
#define SI_ 4
#define EPSf 1e-5f

// triu_indices(11, k=1) pairs
__device__ const int PR[55]={0,0,0,0,0,0,0,0,0,0,1,1,1,1,1,1,1,1,1,2,2,2,2,2,2,2,2,3,3,3,3,3,3,3,4,4,4,4,4,4,5,5,5,5,5,6,6,6,6,7,7,7,8,8,9};
__device__ const int PC[55]={1,2,3,4,5,6,7,8,9,10,2,3,4,5,6,7,8,9,10,3,4,5,6,7,8,9,10,4,5,6,7,8,9,10,5,6,7,8,9,10,6,7,8,9,10,7,8,9,10,8,9,10,9,10,10};

// -------- prep: unified weight matrices Wu/lWu [64 rows][128 k] -------------
// rows 0-47: gate (st*6+g) E-part; rows 48-61: sb_W; rows 62-63: zero
__global__ void k_prep(const float* __restrict__ gW, const float* __restrict__ lgW,
                       const float* __restrict__ sbW, const float* __restrict__ lsbW,
                       float* __restrict__ Wu, float* __restrict__ lWu){
  int k = blockIdx.x*256 + threadIdx.x;
  if (k < 16384){
    int arr = k >> 13, rem = k & 8191;
    int o = rem >> 7, e = rem & 127;
    const float* g = arr ? lgW : gW;
    const float* s = arr ? lsbW : sbW;
    float v;
    if (o < 48) v = g[o*132 + 4 + e];
    else if (o < 62) v = s[(o-48)*128 + e];
    else v = 0.f;
    (arr ? lWu : Wu)[o*128 + e] = v;
  }
}

// -------- fields: gathers + user/item projections ---------------------------
__global__ __launch_bounds__(128) void k_fields(
    const int* __restrict__ cat, const float* __restrict__ num,
    const float* __restrict__ embT, const float* __restrict__ linT,
    const float* __restrict__ uW, const float* __restrict__ ub,
    const float* __restrict__ iW, const float* __restrict__ ib,
    const float* __restrict__ ulW, const float* __restrict__ ulb,
    const float* __restrict__ ilW, const float* __restrict__ ilb,
    float* __restrict__ fields, float* __restrict__ lfields)
{
  const int b = blockIdx.x, e = threadIdx.x;
  __shared__ float s_num[63];
  if (e < 63) s_num[e] = num[(size_t)b*63 + e];
  __syncthreads();
  const int* cb = cat + (size_t)b*10;
  float* fo = fields  + (size_t)b*NF_*E_;
  float* lo = lfields + (size_t)b*NF_*E_;
  for (int j = 0; j < 9; ++j){
    int id = cb[1+j] + j*1000;
    fo[j*E_+e] = embT[(size_t)id*E_+e];
    lo[j*E_+e] = linT[(size_t)id*E_+e];
  }
  float a0 = ub[e], a1 = ulb[e];
  for (int k = 0; k < 23; ++k){ float x = s_num[k]; a0 += x*uW[e*23+k]; a1 += x*ulW[e*23+k]; }
  fo[9*E_+e] = a0; lo[9*E_+e] = a1;
  float a2 = ib[e], a3 = ilb[e];
  for (int k = 0; k < 40; ++k){ float x = s_num[23+k]; a2 += x*iW[e*40+k]; a3 += x*ilW[e*40+k]; }
  fo[10*E_+e] = a2; lo[10*E_+e] = a3;
}

// -------- moe1: pe -> unified GEMM (gate+ein) -> softmax/experts -> w_g -----
// LDS floats: s_pe[56*132]=7392 | s_C[56*68]=3808 (overlays s_fld 1408) |
//             s_w[1760] | s_sh[880] | s_stig[48]   total 13888 (55.5 KB)
__global__ __launch_bounds__(256) void k_moe1(
    const int* __restrict__ cat,
    const float* __restrict__ scen_emb, const float* __restrict__ task_emb,
    const float* __restrict__ st_w, const float* __restrict__ interact_w,
    const float* __restrict__ sb_b,
    const float* __restrict__ shexp_W, const float* __restrict__ shexp_b,
    const float* __restrict__ spexp_W, const float* __restrict__ spexp_b,
    const float* __restrict__ gate_W, const float* __restrict__ gate_b,
    const float* __restrict__ fields, const float* __restrict__ Wu,
    float* __restrict__ w_g)
{
  __shared__ float sm[13888];
  float* s_pe = sm;            // 56 rows x 132
  float* s_C  = sm + 7392;     // 56 rows x 68
  float* s_fld= sm + 7392;     // overlay: 11 x 128 (dead before C written)
  float* s_w  = sm + 11200;    // 8 x 220
  float* s_sh = sm + 12960;    // 55 x 16
  float* s_stig = sm + 13840;  // 48
  const int tid = threadIdx.x, b = blockIdx.x;
  const int scen = cat[(size_t)b*10];

  // stage fields + stig
  for (int idx = tid; idx < 352; idx += 256)
    *(float4*)&s_fld[idx*4] = *(const float4*)&fields[(size_t)b*1408 + idx*4];
  if (tid < 48){
    int st = tid/6, g = tid%6, t = (tid/6)%T_;
    float stw = st_w[t*S_ + scen];
    float acc = gate_b[tid];
    for (int i = 0; i < 4; ++i){
      float sti = scen_emb[scen*4+i] * task_emb[t*4+i] * stw;
      acc += sti * gate_W[tid*132 + i];
    }
    s_stig[tid] = acc;
  }
  __syncthreads();
  // build pe (iw baked in), zero row 55
  for (int idx = tid; idx < 55*32; idx += 256){
    int f = idx >> 5, q = idx & 31;
    float4 r4 = *(const float4*)&s_fld[PR[f]*128 + q*4];
    float4 c4 = *(const float4*)&s_fld[PC[f]*128 + q*4];
    float iw = interact_w[f];
    float4 p; p.x=r4.x*c4.x*iw; p.y=r4.y*c4.y*iw; p.z=r4.z*c4.z*iw; p.w=r4.w*c4.w*iw;
    *(float4*)&s_pe[f*132 + q*4] = p;
  }
  if (tid < 32){ float4 z = {0,0,0,0}; *(float4*)&s_pe[55*132 + tid*4] = z; }
  __syncthreads();

  // unified GEMM: C[56][64] = pe[56][128] * Wu^T, K split 4 ways over lanes
  {
    const int lane = tid & 63, wv_ = tid >> 6;
    const int pair = wv_*16 + (lane & 15);   // 0..63
    const int ks = lane >> 4;                // 0..3
    const int ft = pair & 7, ot = pair >> 3; // 8 x 8 tiles
    const int r0 = ft*7;                     // 7 rows each (8*7=56)
    const int k0 = ks*32;
    float acc[7][8];
    for (int r = 0; r < 7; ++r) for (int c = 0; c < 8; ++c) acc[r][c] = 0.f;
    const float4* Wu4 = (const float4*)Wu;
    #pragma unroll 1
    for (int kc = 0; kc < 32; kc += 4){
      int kk = k0 + kc;
      float4 a[7], wv[8];
      for (int r = 0; r < 7; ++r) a[r] = *(const float4*)&s_pe[(r0+r)*132 + kk];
      for (int c = 0; c < 8; ++c) wv[c] = Wu4[(ot*8+c)*32 + (kk>>2)];
      for (int r = 0; r < 7; ++r)
        for (int c = 0; c < 8; ++c)
          acc[r][c] += a[r].x*wv[c].x + a[r].y*wv[c].y + a[r].z*wv[c].z + a[r].w*wv[c].w;
    }
    for (int r = 0; r < 7; ++r) for (int c = 0; c < 8; ++c){
      float v = acc[r][c];
      v += __shfl_xor(v, 16); v += __shfl_xor(v, 32);
      acc[r][c] = v;
    }
    if (ks == 0){
      for (int r = 0; r < 7; ++r) for (int c = 0; c < 8; ++c){
        int col = ot*8 + c, row = r0 + r;
        float bias = (col < 48) ? s_stig[col] : ((col < 62) ? sb_b[col-48] : 0.f);
        s_C[row*68 + col] = acc[r][c] + bias;
      }
    }
  }
  __syncthreads();
  // shared experts: sh[f][g*4+m] over ein = C[f][48..61]
  for (int o = tid; o < 880; o += 256){
    int f = o >> 4, j = o & 15;
    float acc = shexp_b[j];
    for (int i = 0; i < 14; ++i) acc += s_C[f*68 + 48 + i] * shexp_W[j*14+i];
    s_sh[o] = acc;
  }
  __syncthreads();
  // softmax + specific experts + mixture
  for (int task = tid; task < 440; task += 256){
    int st = task / 55, f = task % 55;
    float lg[6], mx = -1e30f;
    for (int g = 0; g < 6; ++g){ lg[g] = s_C[f*68 + st*6 + g]; mx = fmaxf(mx, lg[g]); }
    float sum = 0.f;
    for (int g = 0; g < 6; ++g){ lg[g] = __expf(lg[g]-mx); sum += lg[g]; }
    float inv = 1.f/sum;
    float wv[4] = {0,0,0,0};
    for (int g = 0; g < 4; ++g){
      float gg = lg[g]*inv;
      for (int m = 0; m < 4; ++m) wv[m] += gg * s_sh[f*16 + g*4 + m];
    }
    for (int ee = 0; ee < 2; ++ee){
      float gg = lg[4+ee]*inv;
      for (int m = 0; m < 4; ++m){
        float acc = spexp_b[(st*2+ee)*4+m];
        const float* wp = spexp_W + ((st*2+ee)*4+m)*14;
        for (int i = 0; i < 14; ++i) acc += s_C[f*68 + 48 + i] * wp[i];
        wv[m] += gg*acc;
      }
    }
    for (int m = 0; m < 4; ++m) s_w[st*220 + f*4 + m] = wv[m];
  }
  __syncthreads();
  // write w_g[b][st][224] (zero-padded cols 220..223), coalesced f4
  for (int idx = tid; idx < 448; idx += 256){
    int st = idx / 56, q = idx % 56;
    float4 v;
    if (q < 55) v = *(float4*)&s_w[st*220 + q*4];
    else { v.x=v.y=v.z=v.w=0.f; }
    *(float4*)&w_g[((size_t)b*8 + st)*224 + q*4] = v;
  }
}

// -------- mask batch GEMM: m1[st*55+oo][b] = mW[st] x w^T + mb --------------
// grid: 512 blocks = 8 st x 64 b-tiles(64). LDS: s_mw[56*116] + s_wb[64*116]
__global__ __launch_bounds__(256) void k_mask(
    const float* __restrict__ w_g, const float* __restrict__ mask_W,
    const float* __restrict__ mask_b, float* __restrict__ m1)
{
  __shared__ float s_mw[56*116];
  __shared__ float s_wb[64*116];
  const int tid = threadIdx.x;
  const int st = blockIdx.x >> 6, bt = blockIdx.x & 63;
  const int b0 = bt*64;
  const int btl = tid & 15, ot = tid >> 4;   // ot<14 active
  float acc[4][4];
  for (int c = 0; c < 4; ++c) for (int j = 0; j < 4; ++j) acc[c][j] = 0.f;

  for (int kc = 0; kc < 2; ++kc){
    __syncthreads();
    for (int idx = tid; idx < 64*112; idx += 256){
      int r = idx / 112, k = idx % 112;
      s_wb[r*116 + k] = w_g[((size_t)(b0+r)*8 + st)*224 + kc*112 + k];
    }
    for (int idx = tid; idx < 56*112; idx += 256){
      int r = idx / 112, k = idx % 112;
      int kg = kc*112 + k;
      s_mw[r*116 + k] = (r < 55 && kg < 220) ? mask_W[((size_t)st*55 + r)*220 + kg] : 0.f;
    }
    __syncthreads();
    if (ot < 14){
      for (int k4 = 0; k4 < 112; k4 += 4){
        float4 a[4], wb[4];
        for (int c = 0; c < 4; ++c) a[c]  = *(float4*)&s_mw[(ot*4+c)*116 + k4];
        for (int j = 0; j < 4; ++j) wb[j] = *(float4*)&s_wb[(btl*4+j)*116 + k4];
        for (int c = 0; c < 4; ++c)
          for (int j = 0; j < 4; ++j)
            acc[c][j] += a[c].x*wb[j].x + a[c].y*wb[j].y + a[c].z*wb[j].z + a[c].w*wb[j].w;
      }
    }
  }
  if (ot < 14){
    for (int c = 0; c < 4; ++c){
      int row = ot*4 + c;
      if (row < 55){
        float mb = mask_b[st*55 + row];
        float4 v; v.x = acc[c][0]+mb; v.y = acc[c][1]+mb; v.z = acc[c][2]+mb; v.w = acc[c][3]+mb;
        *(float4*)&m1[(size_t)(st*55+row)*B_ + b0 + btl*4] = v;
      }
    }
  }
}

// -------- per-row batch stats (mean, rsqrt(var+eps)) ------------------------
__global__ __launch_bounds__(256) void k_stats(const float* __restrict__ x, float* __restrict__ stats){
  const int row = blockIdx.x, tid = threadIdx.x;
  const float* xr = x + (size_t)row*B_;
  float s = 0.f, s2 = 0.f;
  for (int i = tid; i < B_; i += 256){ float v = xr[i]; s += v; s2 += v*v; }
  for (int off = 32; off > 0; off >>= 1){ s += __shfl_down(s, off); s2 += __shfl_down(s2, off); }
  __shared__ float red[8];
  if ((tid & 63) == 0){ red[(tid>>6)*2] = s; red[(tid>>6)*2+1] = s2; }
  __syncthreads();
  if (tid == 0){
    float Ssum = red[0]+red[2]+red[4]+red[6], S2 = red[1]+red[3]+red[5]+red[7];
    float mean = Ssum*(1.f/B_), var = S2*(1.f/B_) - mean*mean;
    stats[row*2] = mean; stats[row*2+1] = rsqrtf(fmaxf(var, 0.f) + EPSf);
  }
}

// -------- inter: bn(m)->tanh->relu, weighted pe contraction -> h[:, :128] ---
__global__ __launch_bounds__(128) void k_inter(
    const int* __restrict__ cat, const float* __restrict__ fields,
    const float* __restrict__ m1, const float* __restrict__ stm,
    const float* __restrict__ att_W, const float* __restrict__ interact_w,
    float* __restrict__ hbuf)
{
  __shared__ float s_fld[NF_*E_];
  __shared__ float s_co[110];
  const int b = blockIdx.x, e = threadIdx.x;
  const int scen = cat[(size_t)b*10];
  for (int k = e; k < NF_*E_; k += 128) s_fld[k] = fields[(size_t)b*NF_*E_ + k];
  if (e < 110){
    int t = e/55, f = e%55, row = (scen*T_+t)*55 + f;
    float v = (m1[(size_t)row*B_+b] - stm[row*2]) * stm[row*2+1];
    v = fmaxf(tanhf(v), 0.f);
    s_co[e] = v * att_W[(scen*T_+t)*55 + f];
  }
  __syncthreads();
  float a0 = 0.f, a1 = 0.f;
  for (int f = 0; f < 55; ++f){
    float pe = s_fld[PR[f]*E_+e] * s_fld[PC[f]*E_+e] * interact_w[f];
    a0 += s_co[f]*pe; a1 += s_co[55+f]*pe;
  }
  hbuf[(size_t)(0*256+e)*B_ + b] = a0;
  hbuf[(size_t)(1*256+e)*B_ + b] = a1;
}

// -------- moe2 (linear path, F=11): unified GEMM + experts + ltower ---------
// LDS floats: s_lf[12*132]=1584 | s_C[12*68]=816 | s_w[352] | s_sh[176] | s_stig[48]
__global__ __launch_bounds__(256) void k_moe2(
    const int* __restrict__ cat,
    const float* __restrict__ scen_emb, const float* __restrict__ task_emb, const float* __restrict__ st_w,
    const float* __restrict__ lsb_b,
    const float* __restrict__ lshexp_W, const float* __restrict__ lshexp_b,
    const float* __restrict__ lspexp_W, const float* __restrict__ lspexp_b,
    const float* __restrict__ lgate_W, const float* __restrict__ lgate_b,
    const float* __restrict__ ltower_W, const float* __restrict__ ltower_b,
    const float* __restrict__ lfields, const float* __restrict__ lWu,
    float* __restrict__ lt1)
{
  __shared__ float sm[2976];
  float* s_lf = sm;            // 12 x 132
  float* s_C  = sm + 1584;     // 12 x 68
  float* s_w  = sm + 2400;     // 8 x 44
  float* s_sh = sm + 2752;     // 11 x 16
  float* s_stig = sm + 2928;   // 48
  const int tid = threadIdx.x, b = blockIdx.x;
  const int scen = cat[(size_t)b*10];

  for (int idx = tid; idx < 352; idx += 256){
    int f = idx >> 5, q = idx & 31;
    *(float4*)&s_lf[f*132 + q*4] = *(const float4*)&lfields[(size_t)b*1408 + f*128 + q*4];
  }
  if (tid >= 256-32 && tid < 256-32+32){ // zero row 11 (any 32 threads)
    int q = tid - (256-32);
    float4 z = {0,0,0,0}; *(float4*)&s_lf[11*132 + q*4] = z;
  }
  if (tid < 48){
    int st = tid/6, g = tid%6, t = (tid/6)%T_;
    float stw = st_w[t*S_ + scen];
    float acc = lgate_b[tid];
    for (int i = 0; i < 4; ++i){
      float sti = scen_emb[scen*4+i] * task_emb[t*4+i] * stw;
      acc += sti * lgate_W[tid*132 + i];
    }
    s_stig[tid] = acc;
  }
  __syncthreads();
  // GEMM on wave 0: C[12][64] = lf[12][128] * lWu^T
  if (tid < 64){
    const int lane = tid;
    const int pair = lane & 15;            // 16 pairs
    const int ks = lane >> 4;              // 4-way K split
    const int ft = pair & 1, ot = pair >> 1; // 2 x 8
    const int r0 = ft*6;
    const int k0 = ks*32;
    float acc[6][8];
    for (int r = 0; r < 6; ++r) for (int c = 0; c < 8; ++c) acc[r][c] = 0.f;
    const float4* W4 = (const float4*)lWu;
    #pragma unroll 1
    for (int kc = 0; kc < 32; kc += 4){
      int kk = k0 + kc;
      float4 a[6], wv[8];
      for (int r = 0; r < 6; ++r) a[r] = *(const float4*)&s_lf[(r0+r)*132 + kk];
      for (int c = 0; c < 8; ++c) wv[c] = W4[(ot*8+c)*32 + (kk>>2)];
      for (int r = 0; r < 6; ++r)
        for (int c = 0; c < 8; ++c)
          acc[r][c] += a[r].x*wv[c].x + a[r].y*wv[c].y + a[r].z*wv[c].z + a[r].w*wv[c].w;
    }
    for (int r = 0; r < 6; ++r) for (int c = 0; c < 8; ++c){
      float v = acc[r][c];
      v += __shfl_xor(v, 16); v += __shfl_xor(v, 32);
      acc[r][c] = v;
    }
    if (ks == 0){
      for (int r = 0; r < 6; ++r) for (int c = 0; c < 8; ++c){
        int col = ot*8 + c, row = r0 + r;
        float bias = (col < 48) ? s_stig[col] : ((col < 62) ? lsb_b[col-48] : 0.f);
        s_C[row*68 + col] = acc[r][c] + bias;
      }
    }
  }
  __syncthreads();
  if (tid < 176){
    int f = tid >> 4, j = tid & 15;
    float acc = lshexp_b[j];
    for (int i = 0; i < 14; ++i) acc += s_C[f*68 + 48 + i] * lshexp_W[j*14+i];
    s_sh[tid] = acc;
  }
  __syncthreads();
  if (tid < 88){
    int st = tid / 11, f = tid % 11;
    float lg[6], mx = -1e30f;
    for (int g = 0; g < 6; ++g){ lg[g] = s_C[f*68 + st*6 + g]; mx = fmaxf(mx, lg[g]); }
    float sum = 0.f;
    for (int g = 0; g < 6; ++g){ lg[g] = __expf(lg[g]-mx); sum += lg[g]; }
    float inv = 1.f/sum;
    float wv[4] = {0,0,0,0};
    for (int g = 0; g < 4; ++g){
      float gg = lg[g]*inv;
      for (int m = 0; m < 4; ++m) wv[m] += gg * s_sh[f*16 + g*4 + m];
    }
    for (int ee = 0; ee < 2; ++ee){
      float gg = lg[4+ee]*inv;
      for (int m = 0; m < 4; ++m){
        float acc = lspexp_b[(st*2+ee)*4+m];
        const float* wp = lspexp_W + ((st*2+ee)*4+m)*14;
        for (int i = 0; i < 14; ++i) acc += s_C[f*68 + 48 + i] * wp[i];
        wv[m] += gg*acc;
      }
    }
    for (int m = 0; m < 4; ++m) s_w[st*44 + f*4 + m] = wv[m];
  }
  __syncthreads();
  if (tid < 88){
    int st = tid / 11, oo = tid % 11;
    float acc = ltower_b[st*11+oo];
    const float* tw = ltower_W + (st*11+oo)*44;
    const float* wp = s_w + st*44;
    for (int i = 0; i < 44; ++i) acc += wp[i] * tw[i];
    lt1[(size_t)(st*11+oo)*B_ + b] = acc;
  }
}

// -------- linf: bn(lt)->softmax over fields, weighted lfields -> h[:,128:] --
__global__ __launch_bounds__(128) void k_linf(
    const int* __restrict__ cat, const float* __restrict__ lfields,
    const float* __restrict__ lt1, const float* __restrict__ stl,
    const float* __restrict__ bias_p, float* __restrict__ hbuf)
{
  __shared__ float s_lf[NF_*E_];
  __shared__ float s_lw[22];
  const int b = blockIdx.x, e = threadIdx.x;
  const int scen = cat[(size_t)b*10];
  for (int k = e; k < NF_*E_; k += 128) s_lf[k] = lfields[(size_t)b*NF_*E_ + k];
  if (e < 22){
    int t = e/11, f = e%11, row = (scen*T_+t)*11 + f;
    s_lw[e] = (lt1[(size_t)row*B_+b] - stl[row*2]) * stl[row*2+1];
  }
  __syncthreads();
  if (e < 2){
    int t = e; float mx = -1e30f;
    for (int f = 0; f < 11; ++f) mx = fmaxf(mx, s_lw[t*11+f]);
    float sum = 0.f;
    for (int f = 0; f < 11; ++f){ float x = __expf(s_lw[t*11+f]-mx); s_lw[t*11+f] = x; sum += x; }
    float inv = 1.f/sum;
    for (int f = 0; f < 11; ++f) s_lw[t*11+f] *= inv;
  }
  __syncthreads();
  for (int t = 0; t < 2; ++t){
    float acc = bias_p[(size_t)(t*S_+scen)*E_ + e];
    for (int f = 0; f < 11; ++f) acc += s_lw[t*11+f] * s_lf[f*E_+e];
    hbuf[(size_t)(t*256+128+e)*B_ + b] = acc;
  }
}

// -------- final MLP ---------------------------------------------------------
__global__ __launch_bounds__(256) void k_last1(const float* __restrict__ hbuf,
    const float* __restrict__ W1, const float* __restrict__ b1, float* __restrict__ h1){
  int bz = blockIdx.x, t = bz/80, r = bz%80, og = r/16, bc = r%16;
  __shared__ float s_w1[8*256];
  int tid = threadIdx.x;
  for (int k = tid; k < 2048; k += 256){
    int oo = k>>8, i = k&255;
    s_w1[k] = W1[(size_t)(t*40 + og*8 + oo)*256 + i];
  }
  __syncthreads();
  int b = bc*256 + tid;
  float acc[8];
  for (int oo = 0; oo < 8; ++oo) acc[oo] = b1[t*40 + og*8 + oo];
  for (int i = 0; i < 256; ++i){
    float hv = hbuf[(size_t)(t*256+i)*B_ + b];
    for (int oo = 0; oo < 8; ++oo) acc[oo] += hv * s_w1[oo*256+i];
  }
  for (int oo = 0; oo < 8; ++oo) h1[(size_t)(t*40 + og*8 + oo)*B_ + b] = acc[oo];
}

__global__ __launch_bounds__(256) void k_last2(const float* __restrict__ h1, const float* __restrict__ st1,
    const float* __restrict__ W2, const float* __restrict__ b2v, float* __restrict__ h2){
  int bz = blockIdx.x, t = bz/16, bc = bz%16, tid = threadIdx.x, b = bc*256 + tid;
  __shared__ float s_w2[1280];
  for (int k = tid; k < 1280; k += 256) s_w2[k] = W2[t*1280 + k];
  __syncthreads();
  float hv[40];
  for (int i = 0; i < 40; ++i){
    int row = t*40 + i;
    hv[i] = fmaxf((h1[(size_t)row*B_+b] - st1[row*2]) * st1[row*2+1], 0.f);
  }
  for (int o = 0; o < 32; ++o){
    float acc = b2v[t*32+o];
    for (int i = 0; i < 40; ++i) acc += hv[i] * s_w2[o*40+i];
    h2[(size_t)(t*32+o)*B_ + b] = acc;
  }
}

__global__ __launch_bounds__(256) void k_last3(const float* __restrict__ h2, const float* __restrict__ st2,
    const float* __restrict__ W3, const float* __restrict__ b3v, float* __restrict__ h3){
  int bz = blockIdx.x, t = bz/16, bc = bz%16, tid = threadIdx.x, b = bc*256 + tid;
  __shared__ float s_w3[256];
  if (tid < 256) s_w3[tid] = W3[t*256 + tid];
  __syncthreads();
  float hv[32];
  for (int i = 0; i < 32; ++i){
    int row = t*32 + i;
    hv[i] = fmaxf((h2[(size_t)row*B_+b] - st2[row*2]) * st2[row*2+1], 0.f);
  }
  for (int o = 0; o < 8; ++o){
    float acc = b3v[t*8+o];
    for (int i = 0; i < 32; ++i) acc += hv[i] * s_w3[o*32+i];
    h3[(size_t)(t*8+o)*B_ + b] = acc;
  }
}

__global__ __launch_bounds__(256) void k_out(const float* __restrict__ h3, const float* __restrict__ st3,
    const float* __restrict__ W4, const float* __restrict__ b4v, float* __restrict__ out){
  int idx = blockIdx.x*256 + threadIdx.x;
  int t = idx / B_, b = idx % B_;
  float acc = b4v[t];
  for (int i = 0; i < 8; ++i){
    int row = t*8 + i;
    float v = fmaxf((h3[(size_t)row*B_+b] - st3[row*2]) * st3[row*2+1], 0.f);
    acc += v * W4[t*8+i];
  }
  out[idx] = 1.f/(1.f + __expf(-acc));
}

extern "C" void kernel_launch(void* const* d_in, const int* in_sizes, int n_in,
                              void* d_out, int out_size, void* d_ws, size_t ws_size,
                              hipStream_t stream)
{
  const int*   cat      = (const int*)  d_in[0];
  const float* num      = (const float*)d_in[1];
  const float* embT     = (const float*)d_in[2];
  const float* linT     = (const float*)d_in[3];
  const float* uW = (const float*)d_in[4];  const float* ub = (const float*)d_in[5];
  const float* iW = (const float*)d_in[6];  const float* ib = (const float*)d_in[7];
  const float* ulW = (const float*)d_in[8]; const float* ulb = (const float*)d_in[9];
  const float* ilW = (const float*)d_in[10];const float* ilb = (const float*)d_in[11];
  const float* scen_emb = (const float*)d_in[12];
  const float* task_emb = (const float*)d_in[13];
  const float* st_w     = (const float*)d_in[14];
  const float* interact_w=(const float*)d_in[15];
  const float* sbW = (const float*)d_in[16]; const float* sbb = (const float*)d_in[17];
  const float* lsbW = (const float*)d_in[18];const float* lsbb = (const float*)d_in[19];
  const float* shW = (const float*)d_in[20]; const float* shb = (const float*)d_in[21];
  const float* spW = (const float*)d_in[22]; const float* spb = (const float*)d_in[23];
  const float* lshW = (const float*)d_in[24];const float* lshb = (const float*)d_in[25];
  const float* lspW = (const float*)d_in[26];const float* lspb = (const float*)d_in[27];
  const float* gW = (const float*)d_in[28];  const float* gb = (const float*)d_in[29];
  const float* lgW = (const float*)d_in[30]; const float* lgb = (const float*)d_in[31];
  const float* mW = (const float*)d_in[32];  const float* mb = (const float*)d_in[33];
  const float* attW = (const float*)d_in[34];
  const float* ltW = (const float*)d_in[35]; const float* ltb = (const float*)d_in[36];
  const float* biasP = (const float*)d_in[37];
  const float* W1 = (const float*)d_in[38];  const float* b1 = (const float*)d_in[39];
  const float* W2 = (const float*)d_in[40];  const float* b2v = (const float*)d_in[41];
  const float* W3 = (const float*)d_in[42];  const float* b3v = (const float*)d_in[43];
  const float* W4 = (const float*)d_in[44];  const float* b4v = (const float*)d_in[45];
  float* out = (float*)d_out;

  float* ws = (float*)d_ws;
  size_t o = 0;
  float* fieldsB  = ws + o; o += (size_t)B_*NF_*E_;
  float* lfieldsB = ws + o; o += (size_t)B_*NF_*E_;
  float* Wu   = ws + o; o += 8192;
  float* lWu  = ws + o; o += 8192;
  float* w_g  = ws + o; o += (size_t)B_*8*224;
  float* m1   = ws + o; o += (size_t)440*B_;
  float* stm  = ws + o; o += 880;
  float* lt1  = ws + o; o += (size_t)88*B_;
  float* stl  = ws + o; o += 176;
  float* hbuf = ws + o; o += (size_t)T_*256*B_;
  float* h1   = ws + o; o += (size_t)80*B_;
  float* st1  = ws + o; o += 160;
  float* h2   = ws + o; o += (size_t)64*B_;
  float* st2  = ws + o; o += 128;
  float* h3   = ws + o; o += (size_t)16*B_;
  float* st3  = ws + o; o += 32;

  k_prep<<<64, 256, 0, stream>>>(gW, lgW, sbW, lsbW, Wu, lWu);
  k_fields<<<B_, 128, 0, stream>>>(cat, num, embT, linT, uW, ub, iW, ib, ulW, ulb, ilW, ilb, fieldsB, lfieldsB);
  k_moe1<<<B_, 256, 0, stream>>>(cat, scen_emb, task_emb, st_w, interact_w, sbb, shW, shb,
                                 spW, spb, gW, gb, fieldsB, Wu, w_g);
  k_mask<<<512, 256, 0, stream>>>(w_g, mW, mb, m1);
  k_stats<<<440, 256, 0, stream>>>(m1, stm);
  k_inter<<<B_, 128, 0, stream>>>(cat, fieldsB, m1, stm, attW, interact_w, hbuf);
  k_moe2<<<B_, 256, 0, stream>>>(cat, scen_emb, task_emb, st_w, lsbb, lshW, lshb,
                                 lspW, lspb, lgW, lgb, ltW, ltb, lfieldsB, lWu, lt1);
  k_stats<<<88, 256, 0, stream>>>(lt1, stl);
  k_linf<<<B_, 128, 0, stream>>>(cat, lfieldsB, lt1, stl, biasP, hbuf);
  k_last1<<<160, 256, 0, stream>>>(hbuf, W1, b1, h1);
  k_stats<<<80, 256, 0, stream>>>(h1, st1);
  k_last2<<<32, 256, 0, stream>>>(h1, st1, W2, b2v, h2);
  k_stats<<<64, 256, 0, stream>>>(h2, st2);
  k_last3<<<32, 256, 0, stream>>>(h2, st2, W3, b3v, h3);
  k_stats<<<16, 256, 0, stream>>>(h3, st3);
  k_out<<<32, 256, 0, stream>>>(h3, st3, W4, b4v, out);
}